// Round 3
// baseline (869.779 us; speedup 1.0000x reference)
//
#include <hip/hip_runtime.h>
#include <hip/hip_bf16.h>

#define TB 2
#define TT 4096
#define TC 2048
#define TM 8192          // B*T
#define THD 64
#define TNCH 64          // chunks per batch

__device__ __forceinline__ float us2f(unsigned short u){
    union { unsigned int u; float f; } x; x.u = ((unsigned int)u) << 16; return x.f;
}
__device__ __forceinline__ unsigned short f2us(float f){
    unsigned int u = __float_as_uint(f);
    unsigned int r = (u + 0x7fffu + ((u >> 16) & 1u)) >> 16;   // RNE bf16
    return (unsigned short)r;
}

// ---------------- lx = hs[:, -1] (fp32) ----------------
__global__ void k_lx(const float* __restrict__ hs, float* __restrict__ o){
    int i = blockIdx.x * 256 + threadIdx.x;
    if (i < TB * TC){
        int b = i >> 11, c = i & (TC - 1);
        o[i] = hs[((size_t)(b * TT + TT - 1)) * TC + c];
    }
}

// ---------------- G1 = tanh(xxx @ w1), xxx on the fly ----------------
// grid (128 n-tiles of 64, 5 j-tiles of 32), 128 threads
__global__ __launch_bounds__(128) void k_gemm1(
    const float* __restrict__ hs, const float* __restrict__ shift,
    const float* __restrict__ maax, const float* __restrict__ w1,
    float* __restrict__ G1)
{
    __shared__ float As[32][68];   // [c][n] transposed
    __shared__ float Bs[32][36];   // [c][j]
    int tid = threadIdx.x;
    int n0 = blockIdx.x * 64;
    int j0 = blockIdx.y * 32;
    int jg = tid & 7, ng = tid >> 3;
    int j_l = jg * 4, n_l = ng * 4;
    float acc[4][4] = {};
    for (int kt = 0; kt < 64; ++kt){
        int c0 = kt * 32;
#pragma unroll
        for (int s = 0; s < 4; ++s){
            int seg = tid + s * 128;          // 512 segs
            int nl = seg >> 3, cl0 = (seg & 7) * 4;
            int n = n0 + nl;
            int t = n & (TT - 1);
            int b = n >> 12;
            float4 h4 = *(const float4*)(hs + (size_t)n * TC + c0 + cl0);
            float4 p4 = (t == 0) ? *(const float4*)(shift + (size_t)b * TC + c0 + cl0)
                                 : *(const float4*)(hs + (size_t)(n - 1) * TC + c0 + cl0);
            float4 m4 = *(const float4*)(maax + c0 + cl0);
            const float* hh = (const float*)&h4;
            const float* pp = (const float*)&p4;
            const float* mm = (const float*)&m4;
#pragma unroll
            for (int ii = 0; ii < 4; ++ii){
                float h = hh[ii];
                As[cl0 + ii][nl] = h + (pp[ii] - h) * mm[ii];
            }
        }
#pragma unroll
        for (int s = 0; s < 2; ++s){
            int seg = tid + s * 128;          // 256 segs
            int cl = seg >> 3, jl0 = (seg & 7) * 4;
            float4 b4 = *(const float4*)(w1 + (size_t)(c0 + cl) * 160 + j0 + jl0);
            const float* bb = (const float*)&b4;
#pragma unroll
            for (int ii = 0; ii < 4; ++ii) Bs[cl][jl0 + ii] = bb[ii];
        }
        __syncthreads();
#pragma unroll 8
        for (int cc = 0; cc < 32; ++cc){
            float4 a4 = *(const float4*)&As[cc][n_l];
            float4 b4 = *(const float4*)&Bs[cc][j_l];
            const float* ap = (const float*)&a4;
            const float* bp = (const float*)&b4;
#pragma unroll
            for (int ii = 0; ii < 4; ++ii)
#pragma unroll
                for (int jj = 0; jj < 4; ++jj) acc[ii][jj] += ap[ii] * bp[jj];
        }
        __syncthreads();
    }
#pragma unroll
    for (int ii = 0; ii < 4; ++ii){
        int n = n0 + n_l + ii;
        float4 o4;
        o4.x = tanhf(acc[ii][0]); o4.y = tanhf(acc[ii][1]);
        o4.z = tanhf(acc[ii][2]); o4.w = tanhf(acc[ii][3]);
        *(float4*)&G1[(size_t)n * 160 + j0 + j_l] = o4;
    }
}

// ---------------- m = G1 @ w2 (per f), X5[f] = hs + xx*(maa_f + m_f) -> bf16 ----------------
// grid (128 n-tiles of 64, 64 c-tiles of 32), 256 threads
__global__ __launch_bounds__(256) void k_mix(
    const float* __restrict__ hs, const float* __restrict__ shift,
    const float* __restrict__ G1, const float* __restrict__ w2,
    const float* __restrict__ maaw, const float* __restrict__ maak,
    const float* __restrict__ maav, const float* __restrict__ maar,
    const float* __restrict__ maag,
    unsigned short* __restrict__ X5)
{
    __shared__ float Gs[64][161];   // [n][fd]  41216 B
    __shared__ float Bs[160][36];   // [fd][c]  23040 B  (total 64256 < 64 KiB)
    int tid = threadIdx.x;
    int n0 = blockIdx.x * 64, c0 = blockIdx.y * 32;
    for (int i = 0; i < 40; ++i){
        int flat = i * 256 + tid;          // 10240 = 64*160
        int r = flat / 160, col = flat % 160;
        Gs[r][col] = G1[(size_t)(n0 + r) * 160 + col];
    }
    for (int i = 0; i < 20; ++i){
        int flat = i * 256 + tid;          // 5120 = 160*32
        int fd = flat >> 5, cl = flat & 31;
        Bs[fd][cl] = w2[(size_t)fd * TC + c0 + cl];
    }
    __syncthreads();
    int cg = tid & 7, ng = tid >> 3;       // 8 c-groups x 32 n-groups
    int c_l = cg * 4, n_l = ng * 2;
    float h[2][4], xx[2][4];
#pragma unroll
    for (int ii = 0; ii < 2; ++ii){
        int n = n0 + n_l + ii;
        int t = n & (TT - 1), b = n >> 12;
        float4 h4 = *(const float4*)(hs + (size_t)n * TC + c0 + c_l);
        float4 p4 = (t == 0) ? *(const float4*)(shift + (size_t)b * TC + c0 + c_l)
                             : *(const float4*)(hs + (size_t)(n - 1) * TC + c0 + c_l);
        const float* hh = (const float*)&h4;
        const float* pp = (const float*)&p4;
#pragma unroll
        for (int jj = 0; jj < 4; ++jj){
            h[ii][jj] = hh[jj];
            xx[ii][jj] = pp[jj] - hh[jj];
        }
    }
    const float* mas[5] = {maaw, maak, maav, maar, maag};
#pragma unroll
    for (int f = 0; f < 5; ++f){
        float acc[2][4] = {};
#pragma unroll 4
        for (int d = 0; d < 32; ++d){
            int fd = f * 32 + d;
            float4 b4 = *(const float4*)&Bs[fd][c_l];
            const float* bb = (const float*)&b4;
            float g0 = Gs[n_l][fd], g1 = Gs[n_l + 1][fd];
#pragma unroll
            for (int jj = 0; jj < 4; ++jj){
                acc[0][jj] += g0 * bb[jj];
                acc[1][jj] += g1 * bb[jj];
            }
        }
        float4 m4 = *(const float4*)(mas[f] + c0 + c_l);
        const float* mm = (const float*)&m4;
        unsigned short* plane = X5 + (size_t)f * TM * TC;
#pragma unroll
        for (int ii = 0; ii < 2; ++ii){
            int n = n0 + n_l + ii;
            ushort4 o4;
            unsigned short* op = (unsigned short*)&o4;
#pragma unroll
            for (int jj = 0; jj < 4; ++jj){
                float xv = h[ii][jj] + xx[ii][jj] * (mm[jj] + acc[ii][jj]);
                op[jj] = f2us(xv);
            }
            *(ushort4*)(plane + (size_t)n * TC + c0 + c_l) = o4;
        }
    }
}

// ---------------- projections: X5[plane](bf16) @ W(fp32) -> fp32 (8192x64) ----------------
// grid (128 n-tiles, 5 mats), 256 threads
__global__ __launch_bounds__(256) void k_proj(
    const unsigned short* __restrict__ X5,
    const float* __restrict__ Wr, const float* __restrict__ Wk,
    const float* __restrict__ Wv, const float* __restrict__ Wg,
    const float* __restrict__ dw1,
    float* __restrict__ rbuf, float* __restrict__ kbuf, float* __restrict__ vbuf,
    float* __restrict__ gpre, float* __restrict__ dpre)
{
    __shared__ float As[32][68];  // [c][n]
    __shared__ float Bs[32][68];  // [c][j]
    int tid = threadIdx.x;
    int n0 = blockIdx.x * 64;
    int mat = blockIdx.y;
    int pI = (mat == 0) ? 3 : (mat == 1) ? 1 : (mat == 2) ? 2 : (mat == 3) ? 4 : 0;
    const unsigned short* A = X5 + (size_t)pI * TM * TC;
    const float* Bm = (mat == 0) ? Wr : (mat == 1) ? Wk : (mat == 2) ? Wv : (mat == 3) ? Wg : dw1;
    float* Out = (mat == 0) ? rbuf : (mat == 1) ? kbuf : (mat == 2) ? vbuf : (mat == 3) ? gpre : dpre;
    int jg = tid & 15, ng = tid >> 4;
    int j_l = jg * 4, n_l = ng * 4;
    float acc[4][4] = {};
    for (int kt = 0; kt < 64; ++kt){
        int c0 = kt * 32;
        {
            int nl = tid >> 2, cl0 = (tid & 3) * 8;
            uint4 au = *(const uint4*)(A + (size_t)(n0 + nl) * TC + c0 + cl0);
            const unsigned short* a8 = (const unsigned short*)&au;
#pragma unroll
            for (int ii = 0; ii < 8; ++ii) As[cl0 + ii][nl] = us2f(a8[ii]);
        }
        {
            int cl = tid >> 3, jl0 = (tid & 7) * 8;
            float4 b0 = *(const float4*)(Bm + (size_t)(c0 + cl) * THD + jl0);
            float4 b1 = *(const float4*)(Bm + (size_t)(c0 + cl) * THD + jl0 + 4);
            const float* f0 = (const float*)&b0;
            const float* f1 = (const float*)&b1;
#pragma unroll
            for (int ii = 0; ii < 4; ++ii){
                Bs[cl][jl0 + ii] = f0[ii];
                Bs[cl][jl0 + 4 + ii] = f1[ii];
            }
        }
        __syncthreads();
#pragma unroll 8
        for (int cc = 0; cc < 32; ++cc){
            float4 a4 = *(const float4*)&As[cc][n_l];
            float4 b4 = *(const float4*)&Bs[cc][j_l];
            const float* ap = (const float*)&a4;
            const float* bp = (const float*)&b4;
#pragma unroll
            for (int ii = 0; ii < 4; ++ii)
#pragma unroll
                for (int jj = 0; jj < 4; ++jj) acc[ii][jj] += ap[ii] * bp[jj];
        }
        __syncthreads();
    }
#pragma unroll
    for (int ii = 0; ii < 4; ++ii){
        int n = n0 + n_l + ii;
        float4 o4; o4.x = acc[ii][0]; o4.y = acc[ii][1]; o4.z = acc[ii][2]; o4.w = acc[ii][3];
        *(float4*)&Out[(size_t)n * THD + j_l] = o4;
    }
}

// ---------------- logw = -exp(time_decay + tanh(dpre) @ dw2) ----------------
__global__ __launch_bounds__(256) void k_wdecay(
    const float* __restrict__ dpre, const float* __restrict__ dw2,
    const float* __restrict__ tdec, float* __restrict__ logwb)
{
    __shared__ float W2s[64][65];
    __shared__ float Ths[16][65];
    int tid = threadIdx.x;
    int n0 = blockIdx.x * 16;
    for (int i = 0; i < 16; ++i){
        int flat = i * 256 + tid;  // 4096
        W2s[flat >> 6][flat & 63] = dw2[flat];
    }
    for (int i = 0; i < 4; ++i){
        int flat = i * 256 + tid;  // 1024
        int tt = flat >> 6, j = flat & 63;
        Ths[tt][j] = tanhf(dpre[(size_t)(n0 + tt) * THD + j]);
    }
    __syncthreads();
    int hh = tid & 63, tg = tid >> 6;
    float td = tdec[hh];
#pragma unroll
    for (int ii = 0; ii < 4; ++ii){
        int tt = tg * 4 + ii;
        float a = 0.f;
#pragma unroll 8
        for (int j = 0; j < 64; ++j) a += Ths[tt][j] * W2s[j][hh];
        logwb[(size_t)(n0 + tt) * THD + hh] = -expf(td + a);
    }
}

// ---------------- scan pass A: per-chunk P (decay product) and I (injection) ----------------
__global__ __launch_bounds__(256) void k_scanA(
    const float* __restrict__ kbuf, const float* __restrict__ vbuf,
    const float* __restrict__ logwb,
    float* __restrict__ chI, float* __restrict__ chP)
{
    __shared__ float kl[32][65], vl[32][65], ewl[32][65];
    int tid = threadIdx.x;
    int b = blockIdx.x >> 6, ch = blockIdx.x & 63;
    int w = tid >> 6, v = tid & 63, kb = w * 16;
    float s[16];
#pragma unroll
    for (int i = 0; i < 16; ++i) s[i] = 0.f;
    float p = 1.f;
    for (int ph = 0; ph < 2; ++ph){
        int t0 = b * TT + ch * 64 + ph * 32;
        for (int i = 0; i < 8; ++i){
            int flat = i * 256 + tid;   // 2048
            int tt = flat >> 6, j = flat & 63;
            size_t g = (size_t)(t0 + tt) * THD + j;
            kl[tt][j] = kbuf[g];
            vl[tt][j] = vbuf[g];
            ewl[tt][j] = expf(logwb[g]);
        }
        __syncthreads();
        if (tid < 64){
#pragma unroll 8
            for (int t = 0; t < 32; ++t) p *= ewl[t][tid];
        }
        for (int t = 0; t < 32; ++t){
            float vv = vl[t][v];
#pragma unroll
            for (int i = 0; i < 16; ++i){
                float e = ewl[t][kb + i], kk = kl[t][kb + i];
                s[i] = s[i] * e + kk * vv;
            }
        }
        __syncthreads();
    }
    size_t base = ((size_t)(b * TNCH + ch)) * THD * THD;
#pragma unroll
    for (int i = 0; i < 16; ++i) chI[base + (size_t)(kb + i) * THD + v] = s[i];
    if (tid < 64) chP[(size_t)(b * TNCH + ch) * THD + tid] = p;
}

// ---------------- scan pass B: sequential chunk-state composition ----------------
__global__ __launch_bounds__(256) void k_scanB(
    const float* __restrict__ chI, const float* __restrict__ chP,
    const float* __restrict__ wkv0,
    float* __restrict__ chS0, float* __restrict__ sfin)
{
    int tid = threadIdx.x;
    int b = blockIdx.x;
    int w = tid >> 6, v = tid & 63, kb = w * 16;
    float s[16];
#pragma unroll
    for (int i = 0; i < 16; ++i)
        s[i] = wkv0[(size_t)b * THD * THD + (size_t)(kb + i) * THD + v];
    for (int ch = 0; ch < TNCH; ++ch){
        size_t base = (size_t)(b * TNCH + ch);
        float P[16], I[16];
#pragma unroll
        for (int i = 0; i < 16; ++i){
            P[i] = chP[base * THD + kb + i];
            I[i] = chI[base * THD * THD + (size_t)(kb + i) * THD + v];
        }
#pragma unroll
        for (int i = 0; i < 16; ++i){
            chS0[base * THD * THD + (size_t)(kb + i) * THD + v] = s[i];
            s[i] = s[i] * P[i] + I[i];
        }
    }
#pragma unroll
    for (int i = 0; i < 16; ++i)
        sfin[(size_t)b * THD * THD + (size_t)(kb + i) * THD + v] = s[i];
}

// ---------------- scan pass C: replay chunks from start state, produce o ----------------
__global__ __launch_bounds__(256) void k_scanC(
    const float* __restrict__ rbuf, const float* __restrict__ kbuf,
    const float* __restrict__ vbuf, const float* __restrict__ logwb,
    const float* __restrict__ chS0, const float* __restrict__ faaaa,
    float* __restrict__ obuf)
{
    __shared__ float rl[32][65], kl[32][65], vl[32][65], ewl[32][65];
    __shared__ float part[4][64];
    __shared__ float ruk[32];
    __shared__ float ul[64];
    int tid = threadIdx.x;
    int b = blockIdx.x >> 6, ch = blockIdx.x & 63;
    int w = tid >> 6, v = tid & 63, kb = w * 16;
    if (tid < 64) ul[tid] = faaaa[tid];
    float s[16];
    {
        size_t base = ((size_t)(b * TNCH + ch)) * THD * THD;
#pragma unroll
        for (int i = 0; i < 16; ++i) s[i] = chS0[base + (size_t)(kb + i) * THD + v];
    }
    for (int ph = 0; ph < 2; ++ph){
        int t0 = b * TT + ch * 64 + ph * 32;
        for (int i = 0; i < 8; ++i){
            int flat = i * 256 + tid;
            int tt = flat >> 6, j = flat & 63;
            size_t g = (size_t)(t0 + tt) * THD + j;
            rl[tt][j] = rbuf[g];
            kl[tt][j] = kbuf[g];
            vl[tt][j] = vbuf[g];
            ewl[tt][j] = expf(logwb[g]);
        }
        __syncthreads();
        if (tid < 32){
            float a = 0.f;
#pragma unroll 8
            for (int k = 0; k < 64; ++k) a += rl[tid][k] * ul[k] * kl[tid][k];
            ruk[tid] = a;
        }
        __syncthreads();
        for (int t = 0; t < 32; ++t){
            float vv = vl[t][v];
            float pp = 0.f;
#pragma unroll
            for (int i = 0; i < 16; ++i) pp += rl[t][kb + i] * s[i];
            part[w][v] = pp;
            __syncthreads();
            if (w == 0){
                float o = part[0][v] + part[1][v] + part[2][v] + part[3][v] + ruk[t] * vv;
                obuf[(size_t)(t0 + t) * THD + v] = o;
            }
#pragma unroll
            for (int i = 0; i < 16; ++i){
                float e = ewl[t][kb + i], kk = kl[t][kb + i];
                s[i] = s[i] * e + kk * vv;
            }
            __syncthreads();
        }
    }
}

// ---------------- out = (o * silu(gpre)) @ W_o -> fp32 ----------------
// grid (128 n-tiles, 32 c-tiles), 256 threads
__global__ __launch_bounds__(256) void k_out(
    const float* __restrict__ obuf, const float* __restrict__ gpre,
    const float* __restrict__ Wo, float* __restrict__ outp)
{
    __shared__ float As[64][68];  // [h][n]
    __shared__ float Bs[64][68];  // [h][c]
    int tid = threadIdx.x;
    int n0 = blockIdx.x * 64, c0 = blockIdx.y * 64;
    for (int i = 0; i < 16; ++i){
        int flat = i * 256 + tid;   // 4096
        int nl = flat >> 6, hh = flat & 63;
        size_t g = (size_t)(n0 + nl) * THD + hh;
        float ov = obuf[g], gv = gpre[g];
        float sg = gv / (1.f + expf(-gv));
        As[hh][nl] = ov * sg;
    }
#pragma unroll
    for (int ss = 0; ss < 4; ++ss){
        int seg = ss * 256 + tid;   // 1024 segs of 4
        int hh = seg >> 4, cl0 = (seg & 15) * 4;
        float4 b4 = *(const float4*)(Wo + (size_t)hh * TC + c0 + cl0);
        const float* bb = (const float*)&b4;
#pragma unroll
        for (int ii = 0; ii < 4; ++ii) Bs[hh][cl0 + ii] = bb[ii];
    }
    __syncthreads();
    int cg = tid & 15, ng = tid >> 4;
    int c_l = cg * 4, n_l = ng * 4;
    float acc[4][4] = {};
#pragma unroll 8
    for (int hh = 0; hh < 64; ++hh){
        float4 a4 = *(const float4*)&As[hh][n_l];
        float4 b4 = *(const float4*)&Bs[hh][c_l];
        const float* ap = (const float*)&a4;
        const float* bp = (const float*)&b4;
#pragma unroll
        for (int ii = 0; ii < 4; ++ii)
#pragma unroll
            for (int jj = 0; jj < 4; ++jj) acc[ii][jj] += ap[ii] * bp[jj];
    }
#pragma unroll
    for (int ii = 0; ii < 4; ++ii){
        int n = n0 + n_l + ii;
        float4 o4;
        o4.x = acc[ii][0]; o4.y = acc[ii][1]; o4.z = acc[ii][2]; o4.w = acc[ii][3];
        *(float4*)&outp[(size_t)n * TC + c0 + c_l] = o4;
    }
}

extern "C" void kernel_launch(void* const* d_in, const int* in_sizes, int n_in,
                              void* d_out, int out_size, void* d_ws, size_t ws_size,
                              hipStream_t stream)
{
    const float* hs    = (const float*)d_in[0];
    const float* shift = (const float*)d_in[1];
    const float* wkv0  = (const float*)d_in[2];
    const float* maax  = (const float*)d_in[3];
    const float* maaw  = (const float*)d_in[4];
    const float* maak  = (const float*)d_in[5];
    const float* maav  = (const float*)d_in[6];
    const float* maar  = (const float*)d_in[7];
    const float* maag  = (const float*)d_in[8];
    const float* w1    = (const float*)d_in[9];
    const float* w2    = (const float*)d_in[10];
    const float* tdec  = (const float*)d_in[11];
    const float* dw1   = (const float*)d_in[12];
    const float* dw2   = (const float*)d_in[13];
    const float* faaaa = (const float*)d_in[14];
    const float* Wr    = (const float*)d_in[15];
    const float* Wk    = (const float*)d_in[16];
    const float* Wv    = (const float*)d_in[17];
    const float* Wg    = (const float*)d_in[18];
    const float* Wo    = (const float*)d_in[19];

    if (ws_size < 191922176ULL) return;

    char* ws = (char*)d_ws;
    float*          G1    = (float*)(ws + 0);                    // 8192*160 f32
    unsigned short* X5    = (unsigned short*)(ws + 5242880);     // 5 planes 8192*2048 bf16
    float*          rbuf  = (float*)(ws + 173015040);
    float*          kbuf  = (float*)(ws + 175112192);
    float*          vbuf  = (float*)(ws + 177209344);
    float*          gpre  = (float*)(ws + 179306496);
    float*          dpre  = (float*)(ws + 181403648);
    float*          logwb = (float*)(ws + 183500800);
    float*          obuf  = (float*)(ws + 185597952);
    float*          chI   = (float*)(ws + 187695104);
    float*          chP   = (float*)(ws + 189792256);
    float*          chS0  = (float*)(ws + 189825024);

    float* outp = (float*)d_out;
    float* lxp  = outp + (size_t)TM * TC;
    float* sfin = lxp + (size_t)TB * TC;

    k_lx    <<<16, 256, 0, stream>>>(hs, lxp);
    k_gemm1 <<<dim3(128, 5), 128, 0, stream>>>(hs, shift, maax, w1, G1);
    k_mix   <<<dim3(128, 64), 256, 0, stream>>>(hs, shift, G1, w2, maaw, maak, maav, maar, maag, X5);
    k_proj  <<<dim3(128, 5), 256, 0, stream>>>(X5, Wr, Wk, Wv, Wg, dw1, rbuf, kbuf, vbuf, gpre, dpre);
    k_wdecay<<<512, 256, 0, stream>>>(dpre, dw2, tdec, logwb);
    k_scanA <<<128, 256, 0, stream>>>(kbuf, vbuf, logwb, chI, chP);
    k_scanB <<<2, 256, 0, stream>>>(chI, chP, wkv0, chS0, sfin);
    k_scanC <<<128, 256, 0, stream>>>(rbuf, kbuf, vbuf, logwb, chS0, faaaa, obuf);
    k_out   <<<dim3(128, 32), 256, 0, stream>>>(obuf, gpre, Wo, outp);
}

// Round 4
// 453.568 us; speedup vs baseline: 1.9176x; 1.9176x over previous
//
#include <hip/hip_runtime.h>
#include <hip/hip_bf16.h>

#define TB 2
#define TT 4096
#define TC 2048
#define TM 8192          // B*T
#define THD 64
#define TNCH 64          // chunks per batch

typedef __attribute__((ext_vector_type(8))) short bf16x8;
typedef __attribute__((ext_vector_type(4))) float f32x4;

__device__ __forceinline__ float us2f(unsigned short u){
    union { unsigned int u; float f; } x; x.u = ((unsigned int)u) << 16; return x.f;
}
__device__ __forceinline__ unsigned short f2us(float f){
    unsigned int u = __float_as_uint(f);
    unsigned int r = (u + 0x7fffu + ((u >> 16) & 1u)) >> 16;   // RNE bf16
    return (unsigned short)r;
}

// ---------------- generic fp32 -> bf16 convert ----------------
__global__ void k_cvt(const float* __restrict__ src, unsigned short* __restrict__ dst, int n4){
    int i = blockIdx.x * 256 + threadIdx.x;
    if (i < n4){
        float4 v = *(const float4*)(src + (size_t)i * 4);
        ushort4 u; u.x = f2us(v.x); u.y = f2us(v.y); u.z = f2us(v.z); u.w = f2us(v.w);
        *(ushort4*)(dst + (size_t)i * 4) = u;
    }
}

// pack {Wr,Wk,Wv,Wg,dw1} -> Wcb[5][2048][64] bf16
__global__ void k_cvt5(const float* __restrict__ s0, const float* __restrict__ s1,
                       const float* __restrict__ s2, const float* __restrict__ s3,
                       const float* __restrict__ s4, unsigned short* __restrict__ dst){
    int i = blockIdx.x * 256 + threadIdx.x;   // over 131072/4 = 32768 float4
    int m = blockIdx.y;
    if (i < 32768){
        const float* s = (m == 0) ? s0 : (m == 1) ? s1 : (m == 2) ? s2 : (m == 3) ? s3 : s4;
        float4 v = *(const float4*)(s + (size_t)i * 4);
        ushort4 u; u.x = f2us(v.x); u.y = f2us(v.y); u.z = f2us(v.z); u.w = f2us(v.w);
        *(ushort4*)(dst + (size_t)m * 131072 + (size_t)i * 4) = u;
    }
}

// ---------------- zero rbuf..dpre (5 x 2 MiB contiguous) ----------------
__global__ void k_zero(float* __restrict__ p){
    int i = blockIdx.x * 256 + threadIdx.x;   // 655360 float4
    if (i < 655360){
        float4 z = {0.f, 0.f, 0.f, 0.f};
        *(float4*)(p + (size_t)i * 4) = z;
    }
}

// ---------------- lx = hs[:, -1] ----------------
__global__ void k_lx(const float* __restrict__ hs, float* __restrict__ o){
    int i = blockIdx.x * 256 + threadIdx.x;
    if (i < TB * TC){
        int b = i >> 11, c = i & (TC - 1);
        o[i] = hs[((size_t)(b * TT + TT - 1)) * TC + c];
    }
}

// ---------------- gemm1 MFMA: Gpart[kc] += xxx[64n x 256k] @ w1b[256k x 160] ----------------
// grid (128 Mtiles, 8 Kchunks), 256 thr
__global__ __launch_bounds__(256) void k_gemm1_mfma(
    const float* __restrict__ hs, const float* __restrict__ shift,
    const float* __restrict__ maax, const unsigned short* __restrict__ w1b,
    float* __restrict__ Gpart)
{
    __shared__ unsigned short As[64 * 40];    // [m][k] pad 40
    __shared__ unsigned short Bs[160 * 40];   // [n][k] pad 40
    int tid = threadIdx.x;
    int wv = tid >> 6, ln = tid & 63;
    int lm = ln & 15, lq = ln >> 4;
    int n0 = blockIdx.x * 64;
    int c0 = blockIdx.y * 256;
    f32x4 zero = {0.f, 0.f, 0.f, 0.f};
    f32x4 acc[10];
#pragma unroll
    for (int i = 0; i < 10; ++i) acc[i] = zero;

    for (int step = 0; step < 8; ++step){
        int kk0 = c0 + step * 32;
        {   // A staging: xxx on the fly
            int m = tid >> 2, kg = (tid & 3) * 8;
            int n = n0 + m; int t = n & (TT - 1); int b = n >> 12;
            const float* hp = hs + (size_t)n * TC + kk0 + kg;
            const float* pp = (t == 0) ? (shift + (size_t)b * TC + kk0 + kg) : (hp - TC);
            float4 h0 = *(const float4*)hp,      h1 = *(const float4*)(hp + 4);
            float4 p0 = *(const float4*)pp,      p1 = *(const float4*)(pp + 4);
            float4 m0 = *(const float4*)(maax + kk0 + kg), m1 = *(const float4*)(maax + kk0 + kg + 4);
            ushort4 ua, ub;
            ua.x = f2us(h0.x + (p0.x - h0.x) * m0.x);
            ua.y = f2us(h0.y + (p0.y - h0.y) * m0.y);
            ua.z = f2us(h0.z + (p0.z - h0.z) * m0.z);
            ua.w = f2us(h0.w + (p0.w - h0.w) * m0.w);
            ub.x = f2us(h1.x + (p1.x - h1.x) * m1.x);
            ub.y = f2us(h1.y + (p1.y - h1.y) * m1.y);
            ub.z = f2us(h1.z + (p1.z - h1.z) * m1.z);
            ub.w = f2us(h1.w + (p1.w - h1.w) * m1.w);
            *(ushort4*)(As + m * 40 + kg) = ua;
            *(ushort4*)(As + m * 40 + kg + 4) = ub;
        }
        // B staging transposed: Bs[n][k] = w1b[kk0+k][n]
        for (int i = tid; i < 640; i += 256){
            int k = i / 20, ng = i % 20;
            uint4 w4 = *(const uint4*)(w1b + (size_t)(kk0 + k) * 160 + ng * 8);
            const unsigned short* ww = (const unsigned short*)&w4;
#pragma unroll
            for (int j = 0; j < 8; ++j) Bs[(ng * 8 + j) * 40 + k] = ww[j];
        }
        __syncthreads();
        bf16x8 af = *(const bf16x8*)(As + (wv * 16 + lm) * 40 + lq * 8);
#pragma unroll
        for (int nt = 0; nt < 10; ++nt){
            bf16x8 bf_ = *(const bf16x8*)(Bs + (nt * 16 + lm) * 40 + lq * 8);
            acc[nt] = __builtin_amdgcn_mfma_f32_16x16x32_bf16(af, bf_, acc[nt], 0, 0, 0);
        }
        __syncthreads();
    }
    float* gp = Gpart + (size_t)blockIdx.y * TM * 160;
#pragma unroll
    for (int nt = 0; nt < 10; ++nt)
#pragma unroll
        for (int i = 0; i < 4; ++i){
            int n = n0 + wv * 16 + lq * 4 + i;
            gp[(size_t)n * 160 + nt * 16 + lm] = acc[nt][i];
        }
}

// ---------------- G1 = tanh(sum Gpart) ----------------
__global__ void k_g1tanh(const float* __restrict__ Gpart, float* __restrict__ G1){
    int i = blockIdx.x * 256 + threadIdx.x;   // 327680 float4
    if (i < 327680){
        float4 s = {0.f, 0.f, 0.f, 0.f};
        for (int kc = 0; kc < 8; ++kc){
            float4 g = *(const float4*)(Gpart + (size_t)kc * TM * 160 + (size_t)i * 4);
            s.x += g.x; s.y += g.y; s.z += g.z; s.w += g.w;
        }
        float4 o; o.x = tanhf(s.x); o.y = tanhf(s.y); o.z = tanhf(s.z); o.w = tanhf(s.w);
        *(float4*)(G1 + (size_t)i * 4) = o;
    }
}

// ---------------- mix MFMA: m[f] = G1[:,f]@w2[f]; X5[f] = hs + xx*(maa_f+m) ----------------
// grid (128 M, 32 N), 256 thr; block 64x64, all 5 f
__global__ __launch_bounds__(256) void k_mix_mfma(
    const float* __restrict__ hs, const float* __restrict__ shift,
    const float* __restrict__ G1, const unsigned short* __restrict__ w2b,
    const float* __restrict__ maaw, const float* __restrict__ maak,
    const float* __restrict__ maav, const float* __restrict__ maar,
    const float* __restrict__ maag,
    unsigned short* __restrict__ X5)
{
    __shared__ unsigned short As[64 * 168];     // G1 bf16 [m][fd] pad 168
    __shared__ unsigned short Bs[5 * 64 * 40];  // [f][n][k] pad 40
    int tid = threadIdx.x;
    int wv = tid >> 6, ln = tid & 63;
    int lm = ln & 15, lq = ln >> 4;
    int n0 = blockIdx.x * 64, c0 = blockIdx.y * 64;

    for (int i = tid; i < 2560; i += 256){      // 64 rows x 40 f4-groups
        int r = i / 40, g = i % 40;
        float4 gv = *(const float4*)(G1 + (size_t)(n0 + r) * 160 + g * 4);
        ushort4 u; u.x = f2us(gv.x); u.y = f2us(gv.y); u.z = f2us(gv.z); u.w = f2us(gv.w);
        *(ushort4*)(As + r * 168 + g * 4) = u;
    }
    for (int i = tid; i < 1280; i += 256){      // 5f x 32k x 8 groups(of 8 n)
        int f = i >> 8, rem = i & 255;
        int k = rem >> 3, g = rem & 7;
        uint4 w4 = *(const uint4*)(w2b + ((size_t)f * 32 + k) * TC + c0 + g * 8);
        const unsigned short* ww = (const unsigned short*)&w4;
#pragma unroll
        for (int j = 0; j < 8; ++j) Bs[f * 2560 + (g * 8 + j) * 40 + k] = ww[j];
    }
    __syncthreads();

    f32x4 zero = {0.f, 0.f, 0.f, 0.f};
    f32x4 acc[5][4];
#pragma unroll
    for (int f = 0; f < 5; ++f){
        bf16x8 af = *(const bf16x8*)(As + (wv * 16 + lm) * 168 + f * 32 + lq * 8);
#pragma unroll
        for (int nt = 0; nt < 4; ++nt){
            bf16x8 bf_ = *(const bf16x8*)(Bs + f * 2560 + (nt * 16 + lm) * 40 + lq * 8);
            acc[f][nt] = __builtin_amdgcn_mfma_f32_16x16x32_bf16(af, bf_, zero, 0, 0, 0);
        }
    }
    // epilogue
    float hv[4][4], dv[4][4];
#pragma unroll
    for (int nt = 0; nt < 4; ++nt){
        int c = c0 + nt * 16 + lm;
#pragma unroll
        for (int i = 0; i < 4; ++i){
            int n = n0 + wv * 16 + lq * 4 + i;
            float h = hs[(size_t)n * TC + c];
            float p = ((n & (TT - 1)) == 0) ? shift[(size_t)(n >> 12) * TC + c]
                                            : hs[(size_t)(n - 1) * TC + c];
            hv[nt][i] = h; dv[nt][i] = p - h;
        }
    }
    const float* mas[5] = {maaw, maak, maav, maar, maag};
#pragma unroll
    for (int f = 0; f < 5; ++f){
        unsigned short* plane = X5 + (size_t)f * TM * TC;
#pragma unroll
        for (int nt = 0; nt < 4; ++nt){
            int c = c0 + nt * 16 + lm;
            float ma = mas[f][c];
#pragma unroll
            for (int i = 0; i < 4; ++i){
                int n = n0 + wv * 16 + lq * 4 + i;
                plane[(size_t)n * TC + c] = f2us(hv[nt][i] + dv[nt][i] * (ma + acc[f][nt][i]));
            }
        }
    }
}

// ---------------- proj MFMA: Out[mat] += X5[plane] @ Wcb[mat]  (K-split 2, atomic) ----------------
// grid (128 M, 5 mats, 2 Khalves), 256 thr
__global__ __launch_bounds__(256) void k_proj_mfma(
    const unsigned short* __restrict__ X5, const unsigned short* __restrict__ Wcb,
    float* __restrict__ rbuf, float* __restrict__ kbuf, float* __restrict__ vbuf,
    float* __restrict__ gpre, float* __restrict__ dpre)
{
    __shared__ unsigned short As[64 * 40];
    __shared__ unsigned short Bs[64 * 40];
    int tid = threadIdx.x;
    int wv = tid >> 6, ln = tid & 63;
    int lm = ln & 15, lq = ln >> 4;
    int n0 = blockIdx.x * 64;
    int mat = blockIdx.y;
    int kh = blockIdx.z;
    int pI = (mat == 0) ? 3 : (mat == 1) ? 1 : (mat == 2) ? 2 : (mat == 3) ? 4 : 0;
    const unsigned short* A = X5 + (size_t)pI * TM * TC;
    const unsigned short* Bm = Wcb + (size_t)mat * TC * THD;
    float* Out = (mat == 0) ? rbuf : (mat == 1) ? kbuf : (mat == 2) ? vbuf : (mat == 3) ? gpre : dpre;

    f32x4 zero = {0.f, 0.f, 0.f, 0.f};
    f32x4 acc[4];
#pragma unroll
    for (int i = 0; i < 4; ++i) acc[i] = zero;

    for (int step = 0; step < 32; ++step){
        int kk0 = kh * 1024 + step * 32;
        {   // A: direct bf16 copy
            int m = tid >> 2, kg = (tid & 3) * 8;
            uint4 a4 = *(const uint4*)(A + (size_t)(n0 + m) * TC + kk0 + kg);
            *(uint4*)(As + m * 40 + kg) = a4;
        }
        {   // B transposed: Bs[n][k] = Bm[kk0+k][n]
            int k = tid >> 3, ng = tid & 7;
            uint4 w4 = *(const uint4*)(Bm + (size_t)(kk0 + k) * THD + ng * 8);
            const unsigned short* ww = (const unsigned short*)&w4;
#pragma unroll
            for (int j = 0; j < 8; ++j) Bs[(ng * 8 + j) * 40 + k] = ww[j];
        }
        __syncthreads();
        bf16x8 af = *(const bf16x8*)(As + (wv * 16 + lm) * 40 + lq * 8);
#pragma unroll
        for (int nt = 0; nt < 4; ++nt){
            bf16x8 bf_ = *(const bf16x8*)(Bs + (nt * 16 + lm) * 40 + lq * 8);
            acc[nt] = __builtin_amdgcn_mfma_f32_16x16x32_bf16(af, bf_, acc[nt], 0, 0, 0);
        }
        __syncthreads();
    }
#pragma unroll
    for (int nt = 0; nt < 4; ++nt)
#pragma unroll
        for (int i = 0; i < 4; ++i){
            int n = n0 + wv * 16 + lq * 4 + i;
            atomicAdd(Out + (size_t)n * THD + nt * 16 + lm, acc[nt][i]);
        }
}

// ---------------- logw = -exp(time_decay + tanh(dpre) @ dw2) ----------------
__global__ __launch_bounds__(256) void k_wdecay(
    const float* __restrict__ dpre, const float* __restrict__ dw2,
    const float* __restrict__ tdec, float* __restrict__ logwb)
{
    __shared__ float W2s[64][65];
    __shared__ float Ths[16][65];
    int tid = threadIdx.x;
    int n0 = blockIdx.x * 16;
    for (int i = 0; i < 16; ++i){
        int flat = i * 256 + tid;
        W2s[flat >> 6][flat & 63] = dw2[flat];
    }
    for (int i = 0; i < 4; ++i){
        int flat = i * 256 + tid;
        int tt = flat >> 6, j = flat & 63;
        Ths[tt][j] = tanhf(dpre[(size_t)(n0 + tt) * THD + j]);
    }
    __syncthreads();
    int hh = tid & 63, tg = tid >> 6;
    float td = tdec[hh];
#pragma unroll
    for (int ii = 0; ii < 4; ++ii){
        int tt = tg * 4 + ii;
        float a = 0.f;
#pragma unroll 8
        for (int j = 0; j < 64; ++j) a += Ths[tt][j] * W2s[j][hh];
        logwb[(size_t)(n0 + tt) * THD + hh] = -expf(td + a);
    }
}

// ---------------- scan pass A ----------------
__global__ __launch_bounds__(256) void k_scanA(
    const float* __restrict__ kbuf, const float* __restrict__ vbuf,
    const float* __restrict__ logwb,
    float* __restrict__ chI, float* __restrict__ chP)
{
    __shared__ float kl[32][65], vl[32][65], ewl[32][65];
    int tid = threadIdx.x;
    int b = blockIdx.x >> 6, ch = blockIdx.x & 63;
    int w = tid >> 6, v = tid & 63, kb = w * 16;
    float s[16];
#pragma unroll
    for (int i = 0; i < 16; ++i) s[i] = 0.f;
    float p = 1.f;
    for (int ph = 0; ph < 2; ++ph){
        int t0 = b * TT + ch * 64 + ph * 32;
        for (int i = 0; i < 8; ++i){
            int flat = i * 256 + tid;
            int tt = flat >> 6, j = flat & 63;
            size_t g = (size_t)(t0 + tt) * THD + j;
            kl[tt][j] = kbuf[g];
            vl[tt][j] = vbuf[g];
            ewl[tt][j] = expf(logwb[g]);
        }
        __syncthreads();
        if (tid < 64){
#pragma unroll 8
            for (int t = 0; t < 32; ++t) p *= ewl[t][tid];
        }
        for (int t = 0; t < 32; ++t){
            float vv = vl[t][v];
#pragma unroll
            for (int i = 0; i < 16; ++i){
                float e = ewl[t][kb + i], kk = kl[t][kb + i];
                s[i] = s[i] * e + kk * vv;
            }
        }
        __syncthreads();
    }
    size_t base = ((size_t)(b * TNCH + ch)) * THD * THD;
#pragma unroll
    for (int i = 0; i < 16; ++i) chI[base + (size_t)(kb + i) * THD + v] = s[i];
    if (tid < 64) chP[(size_t)(b * TNCH + ch) * THD + tid] = p;
}

// ---------------- scan pass B ----------------
__global__ __launch_bounds__(256) void k_scanB(
    const float* __restrict__ chI, const float* __restrict__ chP,
    const float* __restrict__ wkv0,
    float* __restrict__ chS0, float* __restrict__ sfin)
{
    int tid = threadIdx.x;
    int b = blockIdx.x;
    int w = tid >> 6, v = tid & 63, kb = w * 16;
    float s[16];
#pragma unroll
    for (int i = 0; i < 16; ++i)
        s[i] = wkv0[(size_t)b * THD * THD + (size_t)(kb + i) * THD + v];
    for (int ch = 0; ch < TNCH; ++ch){
        size_t base = (size_t)(b * TNCH + ch);
        float P[16], I[16];
#pragma unroll
        for (int i = 0; i < 16; ++i){
            P[i] = chP[base * THD + kb + i];
            I[i] = chI[base * THD * THD + (size_t)(kb + i) * THD + v];
        }
#pragma unroll
        for (int i = 0; i < 16; ++i){
            chS0[base * THD * THD + (size_t)(kb + i) * THD + v] = s[i];
            s[i] = s[i] * P[i] + I[i];
        }
    }
#pragma unroll
    for (int i = 0; i < 16; ++i)
        sfin[(size_t)b * THD * THD + (size_t)(kb + i) * THD + v] = s[i];
}

// ---------------- scan pass C ----------------
__global__ __launch_bounds__(256) void k_scanC(
    const float* __restrict__ rbuf, const float* __restrict__ kbuf,
    const float* __restrict__ vbuf, const float* __restrict__ logwb,
    const float* __restrict__ chS0, const float* __restrict__ faaaa,
    float* __restrict__ obuf)
{
    __shared__ float rl[32][65], kl[32][65], vl[32][65], ewl[32][65];
    __shared__ float part[4][64];
    __shared__ float ruk[32];
    __shared__ float ul[64];
    int tid = threadIdx.x;
    int b = blockIdx.x >> 6, ch = blockIdx.x & 63;
    int w = tid >> 6, v = tid & 63, kb = w * 16;
    if (tid < 64) ul[tid] = faaaa[tid];
    float s[16];
    {
        size_t base = ((size_t)(b * TNCH + ch)) * THD * THD;
#pragma unroll
        for (int i = 0; i < 16; ++i) s[i] = chS0[base + (size_t)(kb + i) * THD + v];
    }
    for (int ph = 0; ph < 2; ++ph){
        int t0 = b * TT + ch * 64 + ph * 32;
        for (int i = 0; i < 8; ++i){
            int flat = i * 256 + tid;
            int tt = flat >> 6, j = flat & 63;
            size_t g = (size_t)(t0 + tt) * THD + j;
            rl[tt][j] = rbuf[g];
            kl[tt][j] = kbuf[g];
            vl[tt][j] = vbuf[g];
            ewl[tt][j] = expf(logwb[g]);
        }
        __syncthreads();
        if (tid < 32){
            float a = 0.f;
#pragma unroll 8
            for (int k = 0; k < 64; ++k) a += rl[tid][k] * ul[k] * kl[tid][k];
            ruk[tid] = a;
        }
        __syncthreads();
        for (int t = 0; t < 32; ++t){
            float vv = vl[t][v];
            float pp = 0.f;
#pragma unroll
            for (int i = 0; i < 16; ++i) pp += rl[t][kb + i] * s[i];
            part[w][v] = pp;
            __syncthreads();
            if (w == 0){
                float o = part[0][v] + part[1][v] + part[2][v] + part[3][v] + ruk[t] * vv;
                obuf[(size_t)(t0 + t) * THD + v] = o;
            }
#pragma unroll
            for (int i = 0; i < 16; ++i){
                float e = ewl[t][kb + i], kk = kl[t][kb + i];
                s[i] = s[i] * e + kk * vv;
            }
            __syncthreads();
        }
    }
}

// ---------------- out MFMA: out = (o*silu(g)) @ Wo ----------------
// grid (128 M, 16 N-tiles of 128), 256 thr
__global__ __launch_bounds__(256) void k_out_mfma(
    const float* __restrict__ obuf, const float* __restrict__ gpre,
    const unsigned short* __restrict__ Wob, float* __restrict__ outp)
{
    __shared__ unsigned short As[64 * 72];    // [m][k=64] pad 72
    __shared__ unsigned short Bs[128 * 72];   // [n][k=64] pad 72
    int tid = threadIdx.x;
    int wv = tid >> 6, ln = tid & 63;
    int lm = ln & 15, lq = ln >> 4;
    int n0 = blockIdx.x * 64, c0 = blockIdx.y * 128;

    for (int i = tid; i < 1024; i += 256){   // 64 rows x 16 f4-groups
        int r = i >> 4, g = i & 15;
        size_t base = (size_t)(n0 + r) * THD + g * 4;
        float4 ov = *(const float4*)(obuf + base);
        float4 gv = *(const float4*)(gpre + base);
        ushort4 u;
        u.x = f2us(ov.x * (gv.x / (1.f + expf(-gv.x))));
        u.y = f2us(ov.y * (gv.y / (1.f + expf(-gv.y))));
        u.z = f2us(ov.z * (gv.z / (1.f + expf(-gv.z))));
        u.w = f2us(ov.w * (gv.w / (1.f + expf(-gv.w))));
        *(ushort4*)(As + r * 72 + g * 4) = u;
    }
    for (int i = tid; i < 1024; i += 256){   // 64 k x 16 groups(of 8 n)
        int k = i >> 4, ng = i & 15;
        uint4 w4 = *(const uint4*)(Wob + (size_t)k * TC + c0 + ng * 8);
        const unsigned short* ww = (const unsigned short*)&w4;
#pragma unroll
        for (int j = 0; j < 8; ++j) Bs[(ng * 8 + j) * 72 + k] = ww[j];
    }
    __syncthreads();

    f32x4 zero = {0.f, 0.f, 0.f, 0.f};
    f32x4 acc[8];
#pragma unroll
    for (int i = 0; i < 8; ++i) acc[i] = zero;
#pragma unroll
    for (int ks = 0; ks < 2; ++ks){
        bf16x8 af = *(const bf16x8*)(As + (wv * 16 + lm) * 72 + ks * 32 + lq * 8);
#pragma unroll
        for (int nt = 0; nt < 8; ++nt){
            bf16x8 bf_ = *(const bf16x8*)(Bs + (nt * 16 + lm) * 72 + ks * 32 + lq * 8);
            acc[nt] = __builtin_amdgcn_mfma_f32_16x16x32_bf16(af, bf_, acc[nt], 0, 0, 0);
        }
    }
#pragma unroll
    for (int nt = 0; nt < 8; ++nt)
#pragma unroll
        for (int i = 0; i < 4; ++i){
            int n = n0 + wv * 16 + lq * 4 + i;
            outp[(size_t)n * TC + c0 + nt * 16 + lm] = acc[nt][i];
        }
}

extern "C" void kernel_launch(void* const* d_in, const int* in_sizes, int n_in,
                              void* d_out, int out_size, void* d_ws, size_t ws_size,
                              hipStream_t stream)
{
    const float* hs    = (const float*)d_in[0];
    const float* shift = (const float*)d_in[1];
    const float* wkv0  = (const float*)d_in[2];
    const float* maax  = (const float*)d_in[3];
    const float* maaw  = (const float*)d_in[4];
    const float* maak  = (const float*)d_in[5];
    const float* maav  = (const float*)d_in[6];
    const float* maar  = (const float*)d_in[7];
    const float* maag  = (const float*)d_in[8];
    const float* w1    = (const float*)d_in[9];
    const float* w2    = (const float*)d_in[10];
    const float* tdec  = (const float*)d_in[11];
    const float* dw1   = (const float*)d_in[12];
    const float* dw2   = (const float*)d_in[13];
    const float* faaaa = (const float*)d_in[14];
    const float* Wr    = (const float*)d_in[15];
    const float* Wk    = (const float*)d_in[16];
    const float* Wv    = (const float*)d_in[17];
    const float* Wg    = (const float*)d_in[18];
    const float* Wo    = (const float*)d_in[19];

    if (ws_size < 186384384ULL) return;

    char* ws = (char*)d_ws;
    unsigned short* w1b  = (unsigned short*)(ws + 0);             // 2048x160
    unsigned short* w2b  = (unsigned short*)(ws + 655360);        // 5x32x2048
    unsigned short* Wcb  = (unsigned short*)(ws + 1310720);       // 5x2048x64 (r,k,v,g,d)
    unsigned short* Wob  = (unsigned short*)(ws + 2621440);       // 64x2048
    float*          G1   = (float*)(ws + 2883584);                // 8192x160 f32
    char*           x5r  = ws + 8126464;                          // 168 MB region
    unsigned short* X5   = (unsigned short*)x5r;                  // 5 planes bf16
    float*          Gpart= (float*)x5r;                           // alias (pre-mix lifetime)
    float*          logwb= (float*)(x5r + 0);                     // alias (post-proj lifetime)
    float*          obuf = (float*)(x5r + 2097152);
    float*          chI  = (float*)(x5r + 4194304);
    float*          chS0 = (float*)(x5r + 6291456);
    float*          chP  = (float*)(x5r + 8388608);
    float*          rbuf = (float*)(ws + 175898624);
    float*          kbuf = (float*)(ws + 177995776);
    float*          vbuf = (float*)(ws + 180092928);
    float*          gpre = (float*)(ws + 182190080);
    float*          dpre = (float*)(ws + 184287232);

    float* outp = (float*)d_out;
    float* lxp  = outp + (size_t)TM * TC;
    float* sfin = lxp + (size_t)TB * TC;

    k_cvt  <<<320, 256, 0, stream>>>(w1, w1b, 81920);
    k_cvt  <<<320, 256, 0, stream>>>(w2, w2b, 81920);
    k_cvt  <<<128, 256, 0, stream>>>(Wo, Wob, 32768);
    k_cvt5 <<<dim3(128, 5), 256, 0, stream>>>(Wr, Wk, Wv, Wg, dw1, Wcb);
    k_zero <<<2560, 256, 0, stream>>>(rbuf);
    k_lx   <<<16, 256, 0, stream>>>(hs, lxp);

    k_gemm1_mfma <<<dim3(128, 8), 256, 0, stream>>>(hs, shift, maax, w1b, Gpart);
    k_g1tanh     <<<1280, 256, 0, stream>>>(Gpart, G1);
    k_mix_mfma   <<<dim3(128, 32), 256, 0, stream>>>(hs, shift, G1, w2b,
                                                     maaw, maak, maav, maar, maag, X5);
    k_proj_mfma  <<<dim3(128, 5, 2), 256, 0, stream>>>(X5, Wcb, rbuf, kbuf, vbuf, gpre, dpre);
    k_wdecay     <<<512, 256, 0, stream>>>(dpre, dw2, tdec, logwb);
    k_scanA      <<<128, 256, 0, stream>>>(kbuf, vbuf, logwb, chI, chP);
    k_scanB      <<<2, 256, 0, stream>>>(chI, chP, wkv0, chS0, sfin);
    k_scanC      <<<128, 256, 0, stream>>>(rbuf, kbuf, vbuf, logwb, chS0, faaaa, obuf);
    k_out_mfma   <<<dim3(128, 16), 256, 0, stream>>>(obuf, gpre, Wob, outp);
}